// Round 15
// baseline (1063.824 us; speedup 1.0000x reference)
//
#include <hip/hip_runtime.h>
#include <math.h>

// Problem constants: B=32, N=320 (T=64+S=256), C=768, H=12, hd=64, Hh=3072
#define NKEEP 179
#define NREM  77
#define NOUT_ROWS 243  // 64 + 179

typedef __bf16 bf16x8 __attribute__((ext_vector_type(8)));
typedef float f32x4 __attribute__((ext_vector_type(4)));

__device__ __forceinline__ unsigned short f2bf(float f) {
  unsigned u = __builtin_bit_cast(unsigned, f);
  u = (u + 0x7FFFu + ((u >> 16) & 1u)) >> 16;
  return (unsigned short)u;
}

__device__ __forceinline__ void gload_lds16(const void* g, void* l) {
  __builtin_amdgcn_global_load_lds((const __attribute__((address_space(1))) void*)g,
                                   (__attribute__((address_space(3))) void*)l,
                                   16, 0, 0);
}

// ---------------------------------------------------------------------------
// LayerNorm. RESID=1 -> out = in + LN(in).
// OUTMODE: 0 = fp32 only, 1 = bf16 only, 2 = fp32 AND bf16.
// ---------------------------------------------------------------------------
template<int RESID, int OUTMODE>
__global__ __launch_bounds__(256)
void ln_kernel(const float* __restrict__ in, const float* __restrict__ gs,
               const float* __restrict__ gb, void* __restrict__ outp,
               void* __restrict__ outp2) {
  int row = blockIdx.x;
  const float* p = in + (size_t)row * 768;
  int tid = threadIdx.x;
  float v0 = p[tid], v1 = p[tid + 256], v2 = p[tid + 512];
  __shared__ double rs[256], rq[256];
  double d0 = v0, d1 = v1, d2 = v2;
  rs[tid] = d0 + d1 + d2;
  rq[tid] = d0 * d0 + d1 * d1 + d2 * d2;
  __syncthreads();
  for (int st = 128; st > 0; st >>= 1) {
    if (tid < st) { rs[tid] += rs[tid + st]; rq[tid] += rq[tid + st]; }
    __syncthreads();
  }
  double mu  = rs[0] * (1.0 / 768.0);
  double var = rq[0] * (1.0 / 768.0) - mu * mu;
  float rstd = (float)rsqrt(var + 1e-5);
  float muf = (float)mu;
  float y0 = (v0 - muf) * rstd * gs[tid]       + gb[tid];
  float y1 = (v1 - muf) * rstd * gs[tid + 256] + gb[tid + 256];
  float y2 = (v2 - muf) * rstd * gs[tid + 512] + gb[tid + 512];
  if (RESID) { y0 += v0; y1 += v1; y2 += v2; }
  if (OUTMODE == 0 || OUTMODE == 2) {
    float* o = (float*)outp + (size_t)row * 768;
    o[tid] = y0; o[tid + 256] = y1; o[tid + 512] = y2;
  }
  if (OUTMODE == 1) {
    unsigned short* o = (unsigned short*)outp + (size_t)row * 768;
    o[tid] = f2bf(y0); o[tid + 256] = f2bf(y1); o[tid + 512] = f2bf(y2);
  }
  if (OUTMODE == 2) {
    unsigned short* o = (unsigned short*)outp2 + (size_t)row * 768;
    o[tid] = f2bf(y0); o[tid + 256] = f2bf(y1); o[tid + 512] = f2bf(y2);
  }
}

// ---------------------------------------------------------------------------
// MERGED weight transpose + bf16 cast: all 5 weights in one dispatch.
// Per-range (bx,by) mapping; body identical for every range (same regalloc).
// ---------------------------------------------------------------------------
__global__ __launch_bounds__(256)
void wtrans_all_kernel(const float* __restrict__ proj_w, unsigned short* __restrict__ proj_wt,
                       const float* __restrict__ fc1_w, unsigned short* __restrict__ fc1_wt,
                       const float* __restrict__ fc2_w, unsigned short* __restrict__ fc2_wt,
                       const float* __restrict__ gcn_w, unsigned short* __restrict__ gcn_wt,
                       const float* __restrict__ qkv_w, unsigned short* __restrict__ qkv_wt) {
  __shared__ float t[32][33];
  int bid = blockIdx.x;
  const float* W; unsigned short* Wt; int K, N, bx, by;
  if (bid < 576)        { W = proj_w; Wt = proj_wt; K = 768;  N = 768;  int i = bid;        bx = i % 24; by = i / 24; }
  else if (bid < 2880)  { W = fc1_w;  Wt = fc1_wt;  K = 768;  N = 3072; int i = bid - 576;  bx = i % 96; by = i / 96; }
  else if (bid < 5184)  { W = fc2_w;  Wt = fc2_wt;  K = 3072; N = 768;  int i = bid - 2880; bx = i % 24; by = i / 24; }
  else if (bid < 5760)  { W = gcn_w;  Wt = gcn_wt;  K = 768;  N = 768;  int i = bid - 5184; bx = i % 24; by = i / 24; }
  else                  { W = qkv_w;  Wt = qkv_wt;  K = 768;  N = 2304; int i = bid - 5760; bx = i % 72; by = i / 72; }
  int n0 = bx * 32, k0 = by * 32;
  int tid = threadIdx.x;
#pragma unroll
  for (int p = 0; p < 4; p++) {
    int idx = tid + p * 256;
    int r = idx >> 5, c = idx & 31;
    t[r][c] = W[(size_t)(k0 + r) * N + n0 + c];
  }
  __syncthreads();
#pragma unroll
  for (int p = 0; p < 4; p++) {
    int idx = tid + p * 256;
    int r = idx >> 5, c = idx & 31;
    Wt[(size_t)(n0 + r) * K + k0 + c] = f2bf(t[c][r]);
  }
}

// ---------------------------------------------------------------------------
// bf16 MFMA GEMM (128xBN tile, BK=64, 4 waves 2x2, 16x16x32 mfma).
// ---------------------------------------------------------------------------
template<int ACT, int RES, int OUTBF, int BN>
__global__ __launch_bounds__(256)
void gemm_bf16_kernel(const unsigned short* __restrict__ A,
                      const unsigned short* __restrict__ Bt,
                      const float* __restrict__ bias, const float* __restrict__ res,
                      void* __restrict__ outp, int M, int K, int N) {
  constexpr int NF = BN / 32;
  __shared__ unsigned short Al[128 * 64];
  __shared__ unsigned short Bl[BN * 64];
  int tid = threadIdx.x;
  int lane = tid & 63, wid = tid >> 6;
  int wr = wid >> 1, wc = wid & 1;
  int bm0 = blockIdx.x * 128, bn0 = blockIdx.y * BN;

  int r8 = lane >> 3;
  int csw = lane & 7;
  int csrc = csw ^ r8;

  const unsigned short* Abase = A + (size_t)bm0 * K + (size_t)csrc * 8;
  const unsigned short* Bbase = Bt + (size_t)bn0 * K + (size_t)csrc * 8;

  f32x4 acc[4][NF] = {};
  int mrow = lane & 15;
  int kch = lane >> 4;
  int key = mrow & 7;

  for (int k0 = 0; k0 < K; k0 += 64) {
#pragma unroll
    for (int i = 0; i < 4; i++) {
      int rr = wid * 32 + i * 8;
      gload_lds16(Abase + (size_t)(rr + r8) * K + k0, Al + rr * 64);
    }
#pragma unroll
    for (int i = 0; i < NF; i++) {
      int rr = wid * (BN / 4) + i * 8;
      gload_lds16(Bbase + (size_t)(rr + r8) * K + k0, Bl + rr * 64);
    }
    __syncthreads();
#pragma unroll
    for (int ks = 0; ks < 2; ks++) {
      bf16x8 af[4], bfr[NF];
#pragma unroll
      for (int f = 0; f < 4; f++) {
        int ra = wr * 64 + f * 16 + mrow;
        int ca = (ks * 4 + kch) ^ key;
        af[f] = *reinterpret_cast<const bf16x8*>(&Al[ra * 64 + ca * 8]);
      }
#pragma unroll
      for (int f = 0; f < NF; f++) {
        int ca = (ks * 4 + kch) ^ key;
        int rb = wc * (BN / 2) + f * 16 + mrow;
        bfr[f] = *reinterpret_cast<const bf16x8*>(&Bl[rb * 64 + ca * 8]);
      }
#pragma unroll
      for (int fm = 0; fm < 4; fm++)
#pragma unroll
        for (int fn = 0; fn < NF; fn++)
          acc[fm][fn] = __builtin_amdgcn_mfma_f32_16x16x32_bf16(
              af[fm], bfr[fn], acc[fm][fn], 0, 0, 0);
    }
    __syncthreads();
  }
#pragma unroll
  for (int fm = 0; fm < 4; fm++) {
#pragma unroll
    for (int j = 0; j < 4; j++) {
      int row = bm0 + wr * 64 + fm * 16 + (lane >> 4) * 4 + j;
#pragma unroll
      for (int fn = 0; fn < NF; fn++) {
        int col = bn0 + wc * (BN / 2) + fn * 16 + (lane & 15);
        float c = acc[fm][fn][j] + bias[col];
        if (ACT == 1) c = 0.5f * c * (1.0f + erff(c * 0.70710678118654752f));
        if (RES) c += res[(size_t)row * N + col];
        if (OUTBF) ((unsigned short*)outp)[(size_t)row * N + col] = f2bf(c);
        else       ((float*)outp)[(size_t)row * N + col] = c;
      }
    }
  }
}

// ---------------------------------------------------------------------------
// bf16 MFMA qkv GEMM (standalone), all 2304 cols. Grid (80, 18).
// ---------------------------------------------------------------------------
__global__ __launch_bounds__(256)
void gemm_qkv_bf16_kernel(const unsigned short* __restrict__ A,
                          const unsigned short* __restrict__ Bt,
                          const float* __restrict__ bias,
                          unsigned short* __restrict__ Qbf,
                          unsigned short* __restrict__ Kbf,
                          float* __restrict__ Vb,
                          unsigned short* __restrict__ Vtbf) {
  __shared__ unsigned short Al[128 * 64];
  __shared__ unsigned short Bl[128 * 64];
  const int K = 768;
  int tid = threadIdx.x;
  int lane = tid & 63, wid = tid >> 6;
  int wr = wid >> 1, wc = wid & 1;
  int colbase = blockIdx.y * 128;
  int bm0 = blockIdx.x * 128;

  int r8 = lane >> 3, csw = lane & 7, csrc = csw ^ r8;
  const unsigned short* Abase = A + (size_t)bm0 * K + (size_t)csrc * 8;
  const unsigned short* Bbase = Bt + (size_t)colbase * K + (size_t)csrc * 8;

  f32x4 acc[4][4] = {};
  int mrow = lane & 15, kch = lane >> 4, key = mrow & 7;

  for (int k0 = 0; k0 < K; k0 += 64) {
#pragma unroll
    for (int i = 0; i < 4; i++) {
      int rr = wid * 32 + i * 8;
      gload_lds16(Abase + (size_t)(rr + r8) * K + k0, Al + rr * 64);
      gload_lds16(Bbase + (size_t)(rr + r8) * K + k0, Bl + rr * 64);
    }
    __syncthreads();
#pragma unroll
    for (int ks = 0; ks < 2; ks++) {
      bf16x8 af[4], bfr[4];
#pragma unroll
      for (int f = 0; f < 4; f++) {
        int ra = wr * 64 + f * 16 + mrow;
        int ca = (ks * 4 + kch) ^ key;
        af[f] = *reinterpret_cast<const bf16x8*>(&Al[ra * 64 + ca * 8]);
        int rb = wc * 64 + f * 16 + mrow;
        bfr[f] = *reinterpret_cast<const bf16x8*>(&Bl[rb * 64 + ca * 8]);
      }
#pragma unroll
      for (int fm = 0; fm < 4; fm++)
#pragma unroll
        for (int fn = 0; fn < 4; fn++)
          acc[fm][fn] = __builtin_amdgcn_mfma_f32_16x16x32_bf16(
              af[fm], bfr[fn], acc[fm][fn], 0, 0, 0);
    }
    __syncthreads();
  }
#pragma unroll
  for (int fm = 0; fm < 4; fm++) {
#pragma unroll
    for (int fn = 0; fn < 4; fn++) {
      int col = colbase + wc * 64 + fn * 16 + (lane & 15);
      int sel = col / 768;
      int rem = col - sel * 768;
      int h = rem >> 6, d = rem & 63;
      int row0 = bm0 + wr * 64 + fm * 16 + (lane >> 4) * 4;
      int b = row0 / 320, nr0 = row0 - b * 320;
      size_t bh = (size_t)(b * 12 + h);
      float v0 = acc[fm][fn][0] + bias[col];
      float v1 = acc[fm][fn][1] + bias[col];
      float v2 = acc[fm][fn][2] + bias[col];
      float v3 = acc[fm][fn][3] + bias[col];
      if (sel == 0) {
        Qbf[(bh * 320 + nr0 + 0) * 64 + d] = f2bf(v0);
        Qbf[(bh * 320 + nr0 + 1) * 64 + d] = f2bf(v1);
        Qbf[(bh * 320 + nr0 + 2) * 64 + d] = f2bf(v2);
        Qbf[(bh * 320 + nr0 + 3) * 64 + d] = f2bf(v3);
      } else if (sel == 1) {
        Kbf[(bh * 320 + nr0 + 0) * 64 + d] = f2bf(v0);
        Kbf[(bh * 320 + nr0 + 1) * 64 + d] = f2bf(v1);
        Kbf[(bh * 320 + nr0 + 2) * 64 + d] = f2bf(v2);
        Kbf[(bh * 320 + nr0 + 3) * 64 + d] = f2bf(v3);
      } else {
        Vb[(bh * 320 + nr0 + 0) * 64 + d] = v0;
        Vb[(bh * 320 + nr0 + 1) * 64 + d] = v1;
        Vb[(bh * 320 + nr0 + 2) * 64 + d] = v2;
        Vb[(bh * 320 + nr0 + 3) * 64 + d] = v3;
        uint2 pk;
        pk.x = (unsigned)f2bf(v0) | ((unsigned)f2bf(v1) << 16);
        pk.y = (unsigned)f2bf(v2) | ((unsigned)f2bf(v3) << 16);
        *(uint2*)&Vtbf[(bh * 64 + d) * 320 + nr0] = pk;
      }
    }
  }
}

// ---------------------------------------------------------------------------
// MERGED precise fp32 GEMM: K (all rows, blocks 0..1919) + Qt (t-rows,
// blocks 1920..2303) in ONE dispatch. Body identical for both ranges
// (runtime rowmap select) -> same 72-VGPR regalloc as the proven kernel.
// BK=16 fp32 chunks + double master, two chunks per BK=32 staging tile.
// ---------------------------------------------------------------------------
__global__ __launch_bounds__(256)
void gemm_prec_all_kernel(const float* __restrict__ A, const float* __restrict__ W,
                          const float* __restrict__ bias,
                          float* __restrict__ Kbuf, float* __restrict__ Qt) {
  __shared__ float As[64 * 32];
  __shared__ float Bs[32 * 64];
  int bid = blockIdx.x;
  int rowmap, bx, by, colOff;
  float* Dst;
  if (bid < 1920) { rowmap = 0; bx = bid % 160; by = bid / 160; colOff = 768; Dst = Kbuf; }
  else            { int i = bid - 1920; rowmap = 1; bx = i % 32; by = i / 32; colOff = 0; Dst = Qt; }

  int tid = threadIdx.x;
  int lane = tid & 63, wid = tid >> 6;
  int tx = tid & 15, ty = tid >> 4;
  int bm0 = bx * 64, bn0 = by * 64;

  int r8 = lane >> 3, csw = lane & 7, csrc = csw ^ r8;
  int aRowG[2];
#pragma unroll
  for (int i = 0; i < 2; i++) {
    int m = bm0 + wid * 16 + i * 8 + r8;
    aRowG[i] = rowmap ? ((m >> 6) * 320 + (m & 63)) : m;
  }
  int br8 = lane >> 4, cch = lane & 15;
  const float* WbaseL = W + colOff + bn0 + cch * 4;

  double master[4][4] = {};
  for (int k0 = 0; k0 < 768; k0 += 32) {
#pragma unroll
    for (int i = 0; i < 2; i++) {
      int rrA = wid * 16 + i * 8;
      gload_lds16(A + (size_t)aRowG[i] * 768 + k0 + csrc * 4, As + rrA * 32);
      int rrB = wid * 8 + i * 4;
      gload_lds16(WbaseL + (size_t)(k0 + rrB + br8) * 2304, Bs + rrB * 64);
    }
    __syncthreads();
#pragma unroll
    for (int half = 0; half < 2; half++) {
      float chunk[4][4] = {};
#pragma unroll
      for (int kg = 0; kg < 4; kg++) {
        int kc = half * 4 + kg;
        float4 a4[4];
#pragma unroll
        for (int i = 0; i < 4; i++) {
          int row = ty * 4 + i;
          a4[i] = *(const float4*)&As[row * 32 + ((kc ^ (row & 7)) << 2)];
        }
#pragma unroll
        for (int c = 0; c < 4; c++) {
          float4 bb = *(const float4*)&Bs[(kc * 4 + c) * 64 + tx * 4];
          float aa[4];
#pragma unroll
          for (int i = 0; i < 4; i++)
            aa[i] = (c == 0) ? a4[i].x : (c == 1) ? a4[i].y
                  : (c == 2) ? a4[i].z : a4[i].w;
#pragma unroll
          for (int i = 0; i < 4; i++) {
            chunk[i][0] = fmaf(aa[i], bb.x, chunk[i][0]);
            chunk[i][1] = fmaf(aa[i], bb.y, chunk[i][1]);
            chunk[i][2] = fmaf(aa[i], bb.z, chunk[i][2]);
            chunk[i][3] = fmaf(aa[i], bb.w, chunk[i][3]);
          }
        }
      }
#pragma unroll
      for (int i = 0; i < 4; i++)
#pragma unroll
        for (int j = 0; j < 4; j++) master[i][j] += (double)chunk[i][j];
    }
    __syncthreads();
  }
  int n0 = bn0 + tx * 4;
  int h = n0 >> 6, d = n0 & 63;
#pragma unroll
  for (int i = 0; i < 4; i++) {
    int m = bm0 + ty * 4 + i;
    float4 v;
    v.x = (float)master[i][0] + bias[colOff + n0];
    v.y = (float)master[i][1] + bias[colOff + n0 + 1];
    v.z = (float)master[i][2] + bias[colOff + n0 + 2];
    v.w = (float)master[i][3] + bias[colOff + n0 + 3];
    if (rowmap) {
      int b = m >> 6, nr = m & 63;
      *(float4*)(Dst + (((size_t)(b * 12 + h) * 64 + nr) << 6) + d) = v;
    } else {
      int b = m / 320, nr = m - b * 320;
      *(float4*)(Dst + (((size_t)(b * 12 + h) * 320 + nr) << 6) + d) = v;
    }
  }
}

// ---------------------------------------------------------------------------
// attn_t: PRECISE t-row attention (standalone, round-12 proven). Grid 384.
// ---------------------------------------------------------------------------
__global__ __launch_bounds__(256)
void attn_t_kernel(const float* __restrict__ Qt, const float* __restrict__ Kb,
                   const float* __restrict__ Vb, float* __restrict__ attn,
                   unsigned short* __restrict__ xa) {
  __shared__ float Qs[64][68];
  __shared__ float Ks[64][68];
  float (*Ps)[68] = Qs;
  int bh = blockIdx.x;
  int h = bh % 12, b = bh / 12;
  int t = threadIdx.x;
  int tx = t & 15, ty = t >> 4;
  const float* Qg = Qt + (size_t)bh * 4096;
  const float* Kg = Kb + (((size_t)bh * 320) << 6);
  const float* Vg = Vb + (((size_t)bh * 320) << 6);
  float* attn_bh = attn + ((size_t)bh * 320) * 320;

  {
    int r = t >> 2, c = (t & 3) * 16;
    const float* src = Qg + (r << 6) + c;
#pragma unroll
    for (int i = 0; i < 4; i++)
      *(float4*)&Qs[r][c + i * 4] = *(const float4*)(src + i * 4);
  }

  float s[4][20];
  float mrow[4] = {-1e30f, -1e30f, -1e30f, -1e30f};

#pragma unroll
  for (int kc = 0; kc < 5; ++kc) {
    __syncthreads();
    {
      int r = t >> 2, c = (t & 3) * 16;
      const float* src = Kg + ((size_t)(kc * 64 + r) << 6) + c;
#pragma unroll
      for (int i = 0; i < 4; i++)
        *(float4*)&Ks[r][c + i * 4] = *(const float4*)(src + i * 4);
    }
    __syncthreads();
    float acc[4][4] = {};
#pragma unroll 4
    for (int d0 = 0; d0 < 64; d0 += 4) {
      float4 qv[4], kv[4];
#pragma unroll
      for (int i = 0; i < 4; i++) qv[i] = *(const float4*)&Qs[ty * 4 + i][d0];
#pragma unroll
      for (int j = 0; j < 4; j++) kv[j] = *(const float4*)&Ks[j * 16 + tx][d0];
#pragma unroll
      for (int i = 0; i < 4; i++)
#pragma unroll
        for (int j = 0; j < 4; j++) {
          acc[i][j] = fmaf(qv[i].x, kv[j].x, acc[i][j]);
          acc[i][j] = fmaf(qv[i].y, kv[j].y, acc[i][j]);
          acc[i][j] = fmaf(qv[i].z, kv[j].z, acc[i][j]);
          acc[i][j] = fmaf(qv[i].w, kv[j].w, acc[i][j]);
        }
    }
#pragma unroll
    for (int i = 0; i < 4; i++) {
      float sx = acc[i][0] * 0.125f, sy = acc[i][1] * 0.125f;
      float sz = acc[i][2] * 0.125f, sw = acc[i][3] * 0.125f;
      mrow[i] = fmaxf(mrow[i], fmaxf(fmaxf(sx, sy), fmaxf(sz, sw)));
      s[i][kc * 4 + 0] = sx; s[i][kc * 4 + 1] = sy;
      s[i][kc * 4 + 2] = sz; s[i][kc * 4 + 3] = sw;
    }
  }
#pragma unroll
  for (int i = 0; i < 4; i++) {
    mrow[i] = fmaxf(mrow[i], __shfl_xor(mrow[i], 1, 16));
    mrow[i] = fmaxf(mrow[i], __shfl_xor(mrow[i], 2, 16));
    mrow[i] = fmaxf(mrow[i], __shfl_xor(mrow[i], 4, 16));
    mrow[i] = fmaxf(mrow[i], __shfl_xor(mrow[i], 8, 16));
  }

  double lsum[4] = {0.0, 0.0, 0.0, 0.0};
#pragma unroll
  for (int i = 0; i < 4; i++)
#pragma unroll
    for (int c = 0; c < 20; c++) {
      float e = expf(s[i][c] - mrow[i]);
      s[i][c] = e;
      lsum[i] += (double)e;
    }
#pragma unroll
  for (int i = 0; i < 4; i++) {
    lsum[i] += __shfl_xor(lsum[i], 1, 16);
    lsum[i] += __shfl_xor(lsum[i], 2, 16);
    lsum[i] += __shfl_xor(lsum[i], 4, 16);
    lsum[i] += __shfl_xor(lsum[i], 8, 16);
  }
  float inv[4];
#pragma unroll
  for (int i = 0; i < 4; i++) inv[i] = (float)(1.0 / lsum[i]);

#pragma unroll
  for (int i = 0; i < 4; i++) {
    float* rp = attn_bh + (size_t)(ty * 4 + i) * 320;
#pragma unroll
    for (int kc = 0; kc < 5; kc++)
#pragma unroll
      for (int j = 0; j < 4; j++)
        rp[kc * 64 + j * 16 + tx] = s[i][kc * 4 + j] * inv[i];
  }

  float acc2[4][4] = {};
  for (int kc = 0; kc < 5; ++kc) {
    __syncthreads();
    {
      int r = t >> 2, c = (t & 3) * 16;
      const float* src = Vg + ((size_t)(kc * 64 + r) << 6) + c;
#pragma unroll
      for (int i = 0; i < 4; i++)
        *(float4*)&Ks[r][c + i * 4] = *(const float4*)(src + i * 4);
    }
#pragma unroll
    for (int i = 0; i < 4; i++)
#pragma unroll
      for (int j = 0; j < 4; j++)
        Ps[ty * 4 + i][j * 16 + tx] = s[i][kc * 4 + j] * inv[i];
    __syncthreads();
#pragma unroll 4
    for (int kk4 = 0; kk4 < 16; ++kk4) {
      float4 pv[4], vv[4];
#pragma unroll
      for (int i = 0; i < 4; i++)
        pv[i] = *(const float4*)&Ps[ty * 4 + i][kk4 * 4];
#pragma unroll
      for (int l = 0; l < 4; l++) vv[l] = *(const float4*)&Ks[kk4 * 4 + l][tx * 4];
#pragma unroll
      for (int i = 0; i < 4; i++) {
        acc2[i][0] = fmaf(pv[i].x, vv[0].x, acc2[i][0]);
        acc2[i][1] = fmaf(pv[i].x, vv[0].y, acc2[i][1]);
        acc2[i][2] = fmaf(pv[i].x, vv[0].z, acc2[i][2]);
        acc2[i][3] = fmaf(pv[i].x, vv[0].w, acc2[i][3]);
        acc2[i][0] = fmaf(pv[i].y, vv[1].x, acc2[i][0]);
        acc2[i][1] = fmaf(pv[i].y, vv[1].y, acc2[i][1]);
        acc2[i][2] = fmaf(pv[i].y, vv[1].z, acc2[i][2]);
        acc2[i][3] = fmaf(pv[i].y, vv[1].w, acc2[i][3]);
        acc2[i][0] = fmaf(pv[i].z, vv[2].x, acc2[i][0]);
        acc2[i][1] = fmaf(pv[i].z, vv[2].y, acc2[i][1]);
        acc2[i][2] = fmaf(pv[i].z, vv[2].z, acc2[i][2]);
        acc2[i][3] = fmaf(pv[i].z, vv[2].w, acc2[i][3]);
        acc2[i][0] = fmaf(pv[i].w, vv[3].x, acc2[i][0]);
        acc2[i][1] = fmaf(pv[i].w, vv[3].y, acc2[i][1]);
        acc2[i][2] = fmaf(pv[i].w, vv[3].z, acc2[i][2]);
        acc2[i][3] = fmaf(pv[i].w, vv[3].w, acc2[i][3]);
      }
    }
  }
#pragma unroll
  for (int i = 0; i < 4; i++) {
    unsigned short* dst = xa + (size_t)(b * 320 + ty * 4 + i) * 768 + h * 64 + tx * 4;
    uint2 pk;
    pk.x = (unsigned)f2bf(acc2[i][0]) | ((unsigned)f2bf(acc2[i][1]) << 16);
    pk.y = (unsigned)f2bf(acc2[i][2]) | ((unsigned)f2bf(acc2[i][3]) << 16);
    *(uint2*)dst = pk;
  }
}

// ---------------------------------------------------------------------------
// attn_s: bf16 MFMA s-row attention (standalone, round-12 proven). Grid 1536.
// ---------------------------------------------------------------------------
__global__ __launch_bounds__(256)
void attn_s_kernel(const unsigned short* __restrict__ Qbf,
                   const unsigned short* __restrict__ Kbf,
                   const unsigned short* __restrict__ Vtbf,
                   float* __restrict__ attn, unsigned short* __restrict__ xa) {
  __shared__ unsigned short lds_[24576];   // 48 KB
  unsigned short* Ql  = lds_;
  unsigned short* Kl  = lds_ + 4096;
  unsigned short* Pl  = lds_;
  unsigned short* Vtl = lds_ + 20480;

  int bid = blockIdx.x;
  int sqt = bid / 384, bh = bid % 384;
  int h = bh % 12, b = bh / 12;
  int q0 = 64 + sqt * 64;
  int tid = threadIdx.x;
  int lane = tid & 63, wid = tid >> 6;
  int r8 = lane >> 3, csw = lane & 7, csrc = csw ^ r8;
  int mrow = lane & 15, kch = lane >> 4, key = mrow & 7;

  const unsigned short* Qg = Qbf + ((size_t)bh * 320 + q0) * 64 + csrc * 8;
  const unsigned short* Kg = Kbf + (size_t)bh * 320 * 64 + csrc * 8;
#pragma unroll
  for (int i = 0; i < 2; i++) {
    int rr = wid * 16 + i * 8;
    gload_lds16(Qg + (size_t)(rr + r8) * 64, Ql + rr * 64);
  }
#pragma unroll
  for (int i = 0; i < 10; i++) {
    int rr = wid * 80 + i * 8;
    gload_lds16(Kg + (size_t)(rr + r8) * 64, Kl + rr * 64);
  }
  __syncthreads();

  bf16x8 af[2];
#pragma unroll
  for (int ks = 0; ks < 2; ks++)
    af[ks] = *reinterpret_cast<const bf16x8*>(
        &Ql[(wid * 16 + mrow) * 64 + (((ks * 4 + kch) ^ key) << 3)]);
  f32x4 acc[20] = {};
#pragma unroll
  for (int nt = 0; nt < 20; nt++) {
#pragma unroll
    for (int ks = 0; ks < 2; ks++) {
      bf16x8 bk = *reinterpret_cast<const bf16x8*>(
          &Kl[(nt * 16 + mrow) * 64 + (((ks * 4 + kch) ^ key) << 3)]);
      acc[nt] = __builtin_amdgcn_mfma_f32_16x16x32_bf16(af[ks], bk, acc[nt], 0, 0, 0);
    }
  }

  float m4[4] = {-1e30f, -1e30f, -1e30f, -1e30f};
#pragma unroll
  for (int nt = 0; nt < 20; nt++)
#pragma unroll
    for (int j = 0; j < 4; j++) {
      acc[nt][j] *= 0.125f;
      m4[j] = fmaxf(m4[j], acc[nt][j]);
    }
#pragma unroll
  for (int j = 0; j < 4; j++) {
    m4[j] = fmaxf(m4[j], __shfl_xor(m4[j], 1, 16));
    m4[j] = fmaxf(m4[j], __shfl_xor(m4[j], 2, 16));
    m4[j] = fmaxf(m4[j], __shfl_xor(m4[j], 4, 16));
    m4[j] = fmaxf(m4[j], __shfl_xor(m4[j], 8, 16));
  }
  float s4[4] = {0.0f, 0.0f, 0.0f, 0.0f};
#pragma unroll
  for (int nt = 0; nt < 20; nt++)
#pragma unroll
    for (int j = 0; j < 4; j++) {
      float e = expf(acc[nt][j] - m4[j]);
      acc[nt][j] = e;
      s4[j] += e;
    }
#pragma unroll
  for (int j = 0; j < 4; j++) {
    s4[j] += __shfl_xor(s4[j], 1, 16);
    s4[j] += __shfl_xor(s4[j], 2, 16);
    s4[j] += __shfl_xor(s4[j], 4, 16);
    s4[j] += __shfl_xor(s4[j], 8, 16);
  }
  float inv4[4];
#pragma unroll
  for (int j = 0; j < 4; j++) inv4[j] = 1.0f / s4[j];

  __syncthreads();

  float* attn_q = attn + ((size_t)bh * 320 + q0) * 320;
#pragma unroll
  for (int j = 0; j < 4; j++) {
    int r = wid * 16 + (lane >> 4) * 4 + j;
    float* rp = attn_q + (size_t)r * 320;
    int rkey = r & 7;
#pragma unroll
    for (int nt = 0; nt < 20; nt++) {
      float p = acc[nt][j] * inv4[j];
      int k = nt * 16 + mrow;
      rp[k] = p;
      int c = k >> 3;
      int cs = (c & 0x38) | ((c ^ rkey) & 7);
      Pl[r * 320 + cs * 8 + (k & 7)] = f2bf(p);
    }
  }

  f32x4 acc2[4] = {};
  const unsigned short* Vg = Vtbf + (size_t)bh * 64 * 320 + csrc * 8;
  for (int kc = 0; kc < 5; kc++) {
    __syncthreads();
#pragma unroll
    for (int i = 0; i < 2; i++) {
      int rr = wid * 16 + i * 8;
      gload_lds16(Vg + (size_t)(rr + r8) * 320 + kc * 64, Vtl + rr * 64);
    }
    __syncthreads();
#pragma unroll
    for (int ks = 0; ks < 2; ks++) {
      int cc = (ks * 4 + kch) ^ key;
      bf16x8 ap = *reinterpret_cast<const bf16x8*>(
          &Pl[(wid * 16 + mrow) * 320 + ((kc * 8 + cc) << 3)]);
#pragma unroll
      for (int nd = 0; nd < 4; nd++) {
        bf16x8 bv = *reinterpret_cast<const bf16x8*>(
            &Vtl[(nd * 16 + mrow) * 64 + (cc << 3)]);
        acc2[nd] = __builtin_amdgcn_mfma_f32_16x16x32_bf16(ap, bv, acc2[nd], 0, 0, 0);
      }
    }
  }
#pragma unroll
  for (int nd = 0; nd < 4; nd++)
#pragma unroll
    for (int j = 0; j < 4; j++) {
      int r = wid * 16 + (lane >> 4) * 4 + j;
      int d = nd * 16 + mrow;
      xa[((size_t)(b * 320) + q0 + r) * 768 + h * 64 + d] = f2bf(acc2[nd][j]);
    }
}

// ---------------------------------------------------------------------------
// w_ts (standalone)
// ---------------------------------------------------------------------------
__global__ __launch_bounds__(256)
void wts_kernel(const float* __restrict__ attn, float* __restrict__ wts) {
  int bid = blockIdx.x;
  int tt = bid & 63, b = bid >> 6;
  int s = threadIdx.x;
  float acc = 0.0f;
  const float* base = attn + (((size_t)(b * 12)) * 320 + tt) * 320 + 64 + s;
#pragma unroll
  for (int h = 0; h < 12; h++) acc += base[(size_t)h * 320 * 320];
  acc *= (1.0f / 12.0f);
  __shared__ float red[256];
  red[s] = acc; __syncthreads();
  for (int st = 128; st > 0; st >>= 1) {
    if (s < st) red[s] = fmaxf(red[s], red[s + st]);
    __syncthreads();
  }
  float m = red[0]; __syncthreads();
  float e = expf(acc - m);
  red[s] = e; __syncthreads();
  for (int st = 128; st > 0; st >>= 1) {
    if (s < st) red[s] += red[s + st];
    __syncthreads();
  }
  wts[(size_t)bid * 256 + s] = e / red[0];
}

// out_t[b,t,c] = sum_s wts[b,t,s] * sup[b,64+s,c]
__global__ __launch_bounds__(256)
void out_t_kernel(const float* __restrict__ wts, const float* __restrict__ sup,
                  float* __restrict__ x3) {
  int idx = blockIdx.x * 256 + threadIdx.x;
  int c = idx % 768;
  int tt = (idx / 768) % 64;
  int b = idx / (768 * 64);
  const float* wrow = wts + (size_t)(b * 64 + tt) * 256;
  const float* sp = sup + ((size_t)(b * 320 + 64)) * 768 + c;
  float acc = 0.0f;
  for (int s = 0; s < 256; s++) acc = fmaf(wrow[s], sp[(size_t)s * 768], acc);
  x3[((size_t)(b * 320 + tt)) * 768 + c] = acc;
}

// out_s[b,s,c] = sum_t wts[b,t,s] * sup[b,t,c]
__global__ __launch_bounds__(256)
void out_s_kernel(const float* __restrict__ wts, const float* __restrict__ sup,
                  float* __restrict__ x3) {
  int idx = blockIdx.x * 256 + threadIdx.x;
  int c = idx % 768;
  int s = (idx / 768) % 256;
  int b = idx / (768 * 256);
  const float* wp = wts + (size_t)(b * 64) * 256 + s;
  const float* sp = sup + ((size_t)(b * 320)) * 768 + c;
  float acc = 0.0f;
#pragma unroll 4
  for (int tt = 0; tt < 64; tt++) acc = fmaf(wp[(size_t)tt * 256], sp[(size_t)tt * 768], acc);
  x3[((size_t)(b * 320 + 64 + s)) * 768 + c] = acc;
}

// ---------------------------------------------------------------------------
// score partials (double) + final stable descending rank-sort + index outs.
// ---------------------------------------------------------------------------
__global__ __launch_bounds__(256)
void score_part_kernel(const float* __restrict__ attn, double* __restrict__ part) {
  int h = blockIdx.x, b = blockIdx.y;
  int s = threadIdx.x;
  const float* base = attn + (((size_t)(b * 12 + h)) * 320) * 320 + 64 + s;
  double acc = 0.0;
  for (int tt = 0; tt < 64; tt++) acc += (double)base[(size_t)tt * 320];
  part[((size_t)(b * 12 + h)) * 256 + s] = acc;
}

__global__ __launch_bounds__(256)
void score_final_kernel(const double* __restrict__ part, const int* __restrict__ git,
                        const int* __restrict__ gis, int* __restrict__ order_ws,
                        float* __restrict__ out_git, float* __restrict__ out_gs,
                        float* __restrict__ out_rm) {
  int b = blockIdx.x, s = threadIdx.x;
  double acc = 0.0;
#pragma unroll
  for (int h = 0; h < 12; h++) acc += part[((size_t)(b * 12 + h)) * 256 + s];
  __shared__ double sc[256];
  __shared__ int ord[256];
  sc[s] = acc;
  __syncthreads();
  double my = sc[s];
  int r = 0;
  for (int i = 0; i < 256; i++) {
    double si = sc[i];
    r += (si > my) || (si == my && i < s);
  }
  ord[r] = s;
  __syncthreads();
  int o = ord[s];
  order_ws[b * 256 + s] = o;
  if (s < NKEEP) out_gs[b * NKEEP + s] = (float)gis[b * 256 + o];
  else           out_rm[b * NREM + (s - NKEEP)] = (float)o;
  if (s < 64)    out_git[b * 64 + s] = (float)git[b * 64 + s];
}

// Final row gather
__global__ __launch_bounds__(256)
void gather_kernel(const float* __restrict__ x3, const int* __restrict__ git,
                   const int* __restrict__ order_ws, float* __restrict__ out) {
  int bid = blockIdx.x;
  int j = bid % NOUT_ROWS, b = bid / NOUT_ROWS;
  int src = (j < 64) ? git[b * 64 + j] : (order_ws[b * 256 + (j - 64)] + 64);
  const float* p = x3 + ((size_t)(b * 320 + src)) * 768;
  float* o = out + ((size_t)(b * NOUT_ROWS + j)) * 768;
  int tid = threadIdx.x;
  o[tid] = p[tid]; o[tid + 256] = p[tid + 256]; o[tid + 512] = p[tid + 512];
}

// ---------------------------------------------------------------------------
extern "C" void kernel_launch(void* const* d_in, const int* in_sizes, int n_in,
                              void* d_out, int out_size, void* d_ws, size_t ws_size,
                              hipStream_t stream) {
  (void)in_sizes; (void)n_in; (void)out_size; (void)ws_size;
  const float* x      = (const float*)d_in[0];
  const int*   git    = (const int*)d_in[1];
  const int*   gis    = (const int*)d_in[2];
  const float* n1s    = (const float*)d_in[3];
  const float* n1b    = (const float*)d_in[4];
  const float* qkv_w  = (const float*)d_in[5];
  const float* qkv_b  = (const float*)d_in[6];
  const float* proj_w = (const float*)d_in[7];
  const float* proj_b = (const float*)d_in[8];
  const float* n2s    = (const float*)d_in[9];
  const float* n2b    = (const float*)d_in[10];
  const float* fc1_w  = (const float*)d_in[11];
  const float* fc1_b  = (const float*)d_in[12];
  const float* fc2_w  = (const float*)d_in[13];
  const float* fc2_b  = (const float*)d_in[14];
  const float* gcn_w  = (const float*)d_in[15];
  const float* gcn_b  = (const float*)d_in[16];
  const float* n3s    = (const float*)d_in[17];
  const float* n3b    = (const float*)d_in[18];

  float* out     = (float*)d_out;
  float* out_x   = out;                 // 32*243*768
  float* out_git = out + 5971968;       // 2048
  float* out_gs  = out + 5974016;       // 5728
  float* out_rm  = out + 5979744;       // 2464
  float* attn    = out + 5982208;       // 32*12*320*320

  float* w      = (float*)d_ws;
  float* bufA   = w;                        // 7,864,320 floats
  float* bufB   = w + 7864320;              // 7,864,320 floats
  float* bufBIG = w + 15728640;             // 31,457,280 floats
  // phase 1 overlay of bufBIG
  float* Qt   = bufBIG;                                         // compact t-row Q
  unsigned short* Vtbf = (unsigned short*)(bufBIG + 1572864);
  float* Kbuf = bufBIG + 7864320;
  float* Vbuf = bufBIG + 15728640;
  unsigned short* ln1_bf = (unsigned short*)(bufBIG + 23592960);
  unsigned short* Qbf = (unsigned short*)bufB;
  unsigned short* Kbf = (unsigned short*)(bufB + 3932160);
  // phase 2 overlay of bufBIG
  unsigned short* f1_bf = (unsigned short*)bufBIG;
  unsigned short* x2_bf = (unsigned short*)(bufBIG + 15728640);
  float* x3 = bufBIG + 19660800;
  // persistent bf16 weights
  unsigned short* wbf = (unsigned short*)(bufBIG + 27525120);
  unsigned short* proj_wt = wbf;
  unsigned short* fc1_wt  = wbf + 589824;
  unsigned short* fc2_wt  = fc1_wt + 2359296;
  unsigned short* gcn_wt  = fc2_wt + 2359296;
  unsigned short* qkv_wt  = gcn_wt + 589824;
  unsigned short* xa_bf = (unsigned short*)bufA;
  unsigned short* h2_bf = (unsigned short*)bufA;
  float* wts    = bufBIG + 31457280;
  int*   order_ws = (int*)(wts + 524288);
  double* partd  = (double*)(wts + 524288 + 8192);

  const int M = 10240;  // 32*320

  // 0. MERGED bf16 weight transposes (one dispatch, 7488 blocks)
  wtrans_all_kernel<<<dim3(7488), dim3(256), 0, stream>>>(
      proj_w, proj_wt, fc1_w, fc1_wt, fc2_w, fc2_wt, gcn_w, gcn_wt, qkv_w, qkv_wt);

  // 1. h = LN1(x): fp32 + bf16
  ln_kernel<0, 2><<<dim3(M), dim3(256), 0, stream>>>(x, n1s, n1b, bufA, ln1_bf);
  // 2a. full qkv in bf16 MFMA
  gemm_qkv_bf16_kernel<<<dim3(80, 18), dim3(256), 0, stream>>>(
      ln1_bf, qkv_wt, qkv_b, Qbf, Kbf, Vbuf, Vtbf);
  // 2b. MERGED precise K + precise Qt (one dispatch, identical bodies)
  gemm_prec_all_kernel<<<dim3(2304), dim3(256), 0, stream>>>(
      bufA, qkv_w, qkv_b, Kbuf, Qt);
  // 3a. precise t-row attention
  attn_t_kernel<<<dim3(384), dim3(256), 0, stream>>>(
      Qt, Kbuf, Vbuf, attn, xa_bf);
  // 3b. bf16 MFMA s-row attention
  attn_s_kernel<<<dim3(1536), dim3(256), 0, stream>>>(
      Qbf, Kbf, Vtbf, attn, xa_bf);
  // 4. x1 = x + xa @ proj_w + proj_b (fp32 -> bufB; Qbf/Kbf now dead)
  gemm_bf16_kernel<0, 1, 0, 64><<<dim3(M / 128, 768 / 64), dim3(256), 0, stream>>>(
      xa_bf, proj_wt, proj_b, x, bufB, M, 768, 768);
  // 5. h2 = LN2(x1) -> bf16
  ln_kernel<0, 1><<<dim3(M), dim3(256), 0, stream>>>(bufB, n2s, n2b, h2_bf, nullptr);
  // 6. f1 = gelu(h2 @ fc1_w + fc1_b) -> bf16
  gemm_bf16_kernel<1, 0, 1, 128><<<dim3(M / 128, 3072 / 128), dim3(256), 0, stream>>>(
      h2_bf, fc1_wt, fc1_b, nullptr, f1_bf, M, 768, 3072);
  // 7. x2 = x1 + f1 @ fc2_w + fc2_b -> bf16
  gemm_bf16_kernel<0, 1, 1, 64><<<dim3(M / 128, 768 / 64), dim3(256), 0, stream>>>(
      f1_bf, fc2_wt, fc2_b, bufB, x2_bf, M, 3072, 768);
  // 8. w_ts
  wts_kernel<<<dim3(32 * 64), dim3(256), 0, stream>>>(attn, wts);
  // 9. support = x2 @ gcn_w + gcn_b (fp32 -> bufA)
  gemm_bf16_kernel<0, 0, 0, 64><<<dim3(M / 128, 768 / 64), dim3(256), 0, stream>>>(
      x2_bf, gcn_wt, gcn_b, nullptr, bufA, M, 768, 768);
  // 10/11. x3 = concat(out_t, out_s)
  out_t_kernel<<<dim3(32 * 64 * 768 / 256), dim3(256), 0, stream>>>(wts, bufA, x3);
  out_s_kernel<<<dim3(32 * 256 * 768 / 256), dim3(256), 0, stream>>>(wts, bufA, x3);
  // 12. x3 = x3 + LN3(x3)
  ln_kernel<1, 0><<<dim3(M), dim3(256), 0, stream>>>(x3, n3s, n3b, x3, nullptr);
  // 13. score partials (double) + final sort
  score_part_kernel<<<dim3(12, 32), dim3(256), 0, stream>>>(attn, partd);
  score_final_kernel<<<dim3(32), dim3(256), 0, stream>>>(partd, git, gis, order_ws,
                                                         out_git, out_gs, out_rm);
  // 14. gather kept rows
  gather_kernel<<<dim3(32 * NOUT_ROWS), dim3(256), 0, stream>>>(x3, git,
                                                                order_ws, out_x);
}

// Round 16
// 896.411 us; speedup vs baseline: 1.1868x; 1.1868x over previous
//
#include <hip/hip_runtime.h>
#include <math.h>

// Problem constants: B=32, N=320 (T=64+S=256), C=768, H=12, hd=64, Hh=3072
#define NKEEP 179
#define NREM  77
#define NOUT_ROWS 243  // 64 + 179

typedef __bf16 bf16x8 __attribute__((ext_vector_type(8)));
typedef float f32x4 __attribute__((ext_vector_type(4)));

__device__ __forceinline__ unsigned short f2bf(float f) {
  unsigned u = __builtin_bit_cast(unsigned, f);
  u = (u + 0x7FFFu + ((u >> 16) & 1u)) >> 16;
  return (unsigned short)u;
}

__device__ __forceinline__ void gload_lds16(const void* g, void* l) {
  __builtin_amdgcn_global_load_lds((const __attribute__((address_space(1))) void*)g,
                                   (__attribute__((address_space(3))) void*)l,
                                   16, 0, 0);
}

// ---------------------------------------------------------------------------
// LayerNorm. RESID=1 -> out = in + LN(in).
// OUTMODE: 0 = fp32 only, 1 = bf16 only, 2 = fp32 AND bf16.
// ---------------------------------------------------------------------------
template<int RESID, int OUTMODE>
__global__ __launch_bounds__(256)
void ln_kernel(const float* __restrict__ in, const float* __restrict__ gs,
               const float* __restrict__ gb, void* __restrict__ outp,
               void* __restrict__ outp2) {
  int row = blockIdx.x;
  const float* p = in + (size_t)row * 768;
  int tid = threadIdx.x;
  float v0 = p[tid], v1 = p[tid + 256], v2 = p[tid + 512];
  __shared__ double rs[256], rq[256];
  double d0 = v0, d1 = v1, d2 = v2;
  rs[tid] = d0 + d1 + d2;
  rq[tid] = d0 * d0 + d1 * d1 + d2 * d2;
  __syncthreads();
  for (int st = 128; st > 0; st >>= 1) {
    if (tid < st) { rs[tid] += rs[tid + st]; rq[tid] += rq[tid + st]; }
    __syncthreads();
  }
  double mu  = rs[0] * (1.0 / 768.0);
  double var = rq[0] * (1.0 / 768.0) - mu * mu;
  float rstd = (float)rsqrt(var + 1e-5);
  float muf = (float)mu;
  float y0 = (v0 - muf) * rstd * gs[tid]       + gb[tid];
  float y1 = (v1 - muf) * rstd * gs[tid + 256] + gb[tid + 256];
  float y2 = (v2 - muf) * rstd * gs[tid + 512] + gb[tid + 512];
  if (RESID) { y0 += v0; y1 += v1; y2 += v2; }
  if (OUTMODE == 0 || OUTMODE == 2) {
    float* o = (float*)outp + (size_t)row * 768;
    o[tid] = y0; o[tid + 256] = y1; o[tid + 512] = y2;
  }
  if (OUTMODE == 1) {
    unsigned short* o = (unsigned short*)outp + (size_t)row * 768;
    o[tid] = f2bf(y0); o[tid + 256] = f2bf(y1); o[tid + 512] = f2bf(y2);
  }
  if (OUTMODE == 2) {
    unsigned short* o = (unsigned short*)outp2 + (size_t)row * 768;
    o[tid] = f2bf(y0); o[tid + 256] = f2bf(y1); o[tid + 512] = f2bf(y2);
  }
}

// ---------------------------------------------------------------------------
// MERGED weight transpose + bf16 cast: all 5 weights in one dispatch.
// ---------------------------------------------------------------------------
__global__ __launch_bounds__(256)
void wtrans_all_kernel(const float* __restrict__ proj_w, unsigned short* __restrict__ proj_wt,
                       const float* __restrict__ fc1_w, unsigned short* __restrict__ fc1_wt,
                       const float* __restrict__ fc2_w, unsigned short* __restrict__ fc2_wt,
                       const float* __restrict__ gcn_w, unsigned short* __restrict__ gcn_wt,
                       const float* __restrict__ qkv_w, unsigned short* __restrict__ qkv_wt) {
  __shared__ float t[32][33];
  int bid = blockIdx.x;
  const float* W; unsigned short* Wt; int K, N, bx, by;
  if (bid < 576)        { W = proj_w; Wt = proj_wt; K = 768;  N = 768;  int i = bid;        bx = i % 24; by = i / 24; }
  else if (bid < 2880)  { W = fc1_w;  Wt = fc1_wt;  K = 768;  N = 3072; int i = bid - 576;  bx = i % 96; by = i / 96; }
  else if (bid < 5184)  { W = fc2_w;  Wt = fc2_wt;  K = 3072; N = 768;  int i = bid - 2880; bx = i % 24; by = i / 24; }
  else if (bid < 5760)  { W = gcn_w;  Wt = gcn_wt;  K = 768;  N = 768;  int i = bid - 5184; bx = i % 24; by = i / 24; }
  else                  { W = qkv_w;  Wt = qkv_wt;  K = 768;  N = 2304; int i = bid - 5760; bx = i % 72; by = i / 72; }
  int n0 = bx * 32, k0 = by * 32;
  int tid = threadIdx.x;
#pragma unroll
  for (int p = 0; p < 4; p++) {
    int idx = tid + p * 256;
    int r = idx >> 5, c = idx & 31;
    t[r][c] = W[(size_t)(k0 + r) * N + n0 + c];
  }
  __syncthreads();
#pragma unroll
  for (int p = 0; p < 4; p++) {
    int idx = tid + p * 256;
    int r = idx >> 5, c = idx & 31;
    Wt[(size_t)(n0 + r) * K + k0 + c] = f2bf(t[c][r]);
  }
}

// ---------------------------------------------------------------------------
// bf16 MFMA GEMM (128xBN tile, BK=64, 4 waves 2x2, 16x16x32 mfma).
// ---------------------------------------------------------------------------
template<int ACT, int RES, int OUTBF, int BN>
__global__ __launch_bounds__(256)
void gemm_bf16_kernel(const unsigned short* __restrict__ A,
                      const unsigned short* __restrict__ Bt,
                      const float* __restrict__ bias, const float* __restrict__ res,
                      void* __restrict__ outp, int M, int K, int N) {
  constexpr int NF = BN / 32;
  __shared__ unsigned short Al[128 * 64];
  __shared__ unsigned short Bl[BN * 64];
  int tid = threadIdx.x;
  int lane = tid & 63, wid = tid >> 6;
  int wr = wid >> 1, wc = wid & 1;
  int bm0 = blockIdx.x * 128, bn0 = blockIdx.y * BN;

  int r8 = lane >> 3;
  int csw = lane & 7;
  int csrc = csw ^ r8;

  const unsigned short* Abase = A + (size_t)bm0 * K + (size_t)csrc * 8;
  const unsigned short* Bbase = Bt + (size_t)bn0 * K + (size_t)csrc * 8;

  f32x4 acc[4][NF] = {};
  int mrow = lane & 15;
  int kch = lane >> 4;
  int key = mrow & 7;

  for (int k0 = 0; k0 < K; k0 += 64) {
#pragma unroll
    for (int i = 0; i < 4; i++) {
      int rr = wid * 32 + i * 8;
      gload_lds16(Abase + (size_t)(rr + r8) * K + k0, Al + rr * 64);
    }
#pragma unroll
    for (int i = 0; i < NF; i++) {
      int rr = wid * (BN / 4) + i * 8;
      gload_lds16(Bbase + (size_t)(rr + r8) * K + k0, Bl + rr * 64);
    }
    __syncthreads();
#pragma unroll
    for (int ks = 0; ks < 2; ks++) {
      bf16x8 af[4], bfr[NF];
#pragma unroll
      for (int f = 0; f < 4; f++) {
        int ra = wr * 64 + f * 16 + mrow;
        int ca = (ks * 4 + kch) ^ key;
        af[f] = *reinterpret_cast<const bf16x8*>(&Al[ra * 64 + ca * 8]);
      }
#pragma unroll
      for (int f = 0; f < NF; f++) {
        int ca = (ks * 4 + kch) ^ key;
        int rb = wc * (BN / 2) + f * 16 + mrow;
        bfr[f] = *reinterpret_cast<const bf16x8*>(&Bl[rb * 64 + ca * 8]);
      }
#pragma unroll
      for (int fm = 0; fm < 4; fm++)
#pragma unroll
        for (int fn = 0; fn < NF; fn++)
          acc[fm][fn] = __builtin_amdgcn_mfma_f32_16x16x32_bf16(
              af[fm], bfr[fn], acc[fm][fn], 0, 0, 0);
    }
    __syncthreads();
  }
#pragma unroll
  for (int fm = 0; fm < 4; fm++) {
#pragma unroll
    for (int j = 0; j < 4; j++) {
      int row = bm0 + wr * 64 + fm * 16 + (lane >> 4) * 4 + j;
#pragma unroll
      for (int fn = 0; fn < NF; fn++) {
        int col = bn0 + wc * (BN / 2) + fn * 16 + (lane & 15);
        float c = acc[fm][fn][j] + bias[col];
        if (ACT == 1) c = 0.5f * c * (1.0f + erff(c * 0.70710678118654752f));
        if (RES) c += res[(size_t)row * N + col];
        if (OUTBF) ((unsigned short*)outp)[(size_t)row * N + col] = f2bf(c);
        else       ((float*)outp)[(size_t)row * N + col] = c;
      }
    }
  }
}

// ---------------------------------------------------------------------------
// bf16 MFMA qkv GEMM (standalone), all 2304 cols. Grid (80, 18).
// ---------------------------------------------------------------------------
__global__ __launch_bounds__(256)
void gemm_qkv_bf16_kernel(const unsigned short* __restrict__ A,
                          const unsigned short* __restrict__ Bt,
                          const float* __restrict__ bias,
                          unsigned short* __restrict__ Qbf,
                          unsigned short* __restrict__ Kbf,
                          float* __restrict__ Vb,
                          unsigned short* __restrict__ Vtbf) {
  __shared__ unsigned short Al[128 * 64];
  __shared__ unsigned short Bl[128 * 64];
  const int K = 768;
  int tid = threadIdx.x;
  int lane = tid & 63, wid = tid >> 6;
  int wr = wid >> 1, wc = wid & 1;
  int colbase = blockIdx.y * 128;
  int bm0 = blockIdx.x * 128;

  int r8 = lane >> 3, csw = lane & 7, csrc = csw ^ r8;
  const unsigned short* Abase = A + (size_t)bm0 * K + (size_t)csrc * 8;
  const unsigned short* Bbase = Bt + (size_t)colbase * K + (size_t)csrc * 8;

  f32x4 acc[4][4] = {};
  int mrow = lane & 15, kch = lane >> 4, key = mrow & 7;

  for (int k0 = 0; k0 < K; k0 += 64) {
#pragma unroll
    for (int i = 0; i < 4; i++) {
      int rr = wid * 32 + i * 8;
      gload_lds16(Abase + (size_t)(rr + r8) * K + k0, Al + rr * 64);
      gload_lds16(Bbase + (size_t)(rr + r8) * K + k0, Bl + rr * 64);
    }
    __syncthreads();
#pragma unroll
    for (int ks = 0; ks < 2; ks++) {
      bf16x8 af[4], bfr[4];
#pragma unroll
      for (int f = 0; f < 4; f++) {
        int ra = wr * 64 + f * 16 + mrow;
        int ca = (ks * 4 + kch) ^ key;
        af[f] = *reinterpret_cast<const bf16x8*>(&Al[ra * 64 + ca * 8]);
        int rb = wc * 64 + f * 16 + mrow;
        bfr[f] = *reinterpret_cast<const bf16x8*>(&Bl[rb * 64 + ca * 8]);
      }
#pragma unroll
      for (int fm = 0; fm < 4; fm++)
#pragma unroll
        for (int fn = 0; fn < 4; fn++)
          acc[fm][fn] = __builtin_amdgcn_mfma_f32_16x16x32_bf16(
              af[fm], bfr[fn], acc[fm][fn], 0, 0, 0);
    }
    __syncthreads();
  }
#pragma unroll
  for (int fm = 0; fm < 4; fm++) {
#pragma unroll
    for (int fn = 0; fn < 4; fn++) {
      int col = colbase + wc * 64 + fn * 16 + (lane & 15);
      int sel = col / 768;
      int rem = col - sel * 768;
      int h = rem >> 6, d = rem & 63;
      int row0 = bm0 + wr * 64 + fm * 16 + (lane >> 4) * 4;
      int b = row0 / 320, nr0 = row0 - b * 320;
      size_t bh = (size_t)(b * 12 + h);
      float v0 = acc[fm][fn][0] + bias[col];
      float v1 = acc[fm][fn][1] + bias[col];
      float v2 = acc[fm][fn][2] + bias[col];
      float v3 = acc[fm][fn][3] + bias[col];
      if (sel == 0) {
        Qbf[(bh * 320 + nr0 + 0) * 64 + d] = f2bf(v0);
        Qbf[(bh * 320 + nr0 + 1) * 64 + d] = f2bf(v1);
        Qbf[(bh * 320 + nr0 + 2) * 64 + d] = f2bf(v2);
        Qbf[(bh * 320 + nr0 + 3) * 64 + d] = f2bf(v3);
      } else if (sel == 1) {
        Kbf[(bh * 320 + nr0 + 0) * 64 + d] = f2bf(v0);
        Kbf[(bh * 320 + nr0 + 1) * 64 + d] = f2bf(v1);
        Kbf[(bh * 320 + nr0 + 2) * 64 + d] = f2bf(v2);
        Kbf[(bh * 320 + nr0 + 3) * 64 + d] = f2bf(v3);
      } else {
        Vb[(bh * 320 + nr0 + 0) * 64 + d] = v0;
        Vb[(bh * 320 + nr0 + 1) * 64 + d] = v1;
        Vb[(bh * 320 + nr0 + 2) * 64 + d] = v2;
        Vb[(bh * 320 + nr0 + 3) * 64 + d] = v3;
        uint2 pk;
        pk.x = (unsigned)f2bf(v0) | ((unsigned)f2bf(v1) << 16);
        pk.y = (unsigned)f2bf(v2) | ((unsigned)f2bf(v3) << 16);
        *(uint2*)&Vtbf[(bh * 64 + d) * 320 + nr0] = pk;
      }
    }
  }
}

// ---------------------------------------------------------------------------
// Precise fp32 GEMM (TEMPLATED — compile-time ROWMAP keeps 72-VGPR alloc).
// BK=16 fp32 chunks + double master, two chunks per BK=32 staging tile.
// ROWMAP=0 -> head-major [bh][320][64]; ROWMAP=1 -> compact Qt [bh][64][64].
// ---------------------------------------------------------------------------
template<int ROWMAP>
__global__ __launch_bounds__(256)
void gemm_prec_kernel(const float* __restrict__ A, const float* __restrict__ W,
                      const float* __restrict__ bias, int colOff,
                      float* __restrict__ Dst) {
  __shared__ float As[64 * 32];
  __shared__ float Bs[32 * 64];
  int tid = threadIdx.x;
  int lane = tid & 63, wid = tid >> 6;
  int tx = tid & 15, ty = tid >> 4;
  int bm0 = blockIdx.x * 64, bn0 = blockIdx.y * 64;

  int r8 = lane >> 3, csw = lane & 7, csrc = csw ^ r8;
  int aRowG[2];
#pragma unroll
  for (int i = 0; i < 2; i++) {
    int m = bm0 + wid * 16 + i * 8 + r8;
    aRowG[i] = ROWMAP ? ((m >> 6) * 320 + (m & 63)) : m;
  }
  int br8 = lane >> 4, cch = lane & 15;
  const float* WbaseL = W + colOff + bn0 + cch * 4;

  double master[4][4] = {};
  for (int k0 = 0; k0 < 768; k0 += 32) {
#pragma unroll
    for (int i = 0; i < 2; i++) {
      int rrA = wid * 16 + i * 8;
      gload_lds16(A + (size_t)aRowG[i] * 768 + k0 + csrc * 4, As + rrA * 32);
      int rrB = wid * 8 + i * 4;
      gload_lds16(WbaseL + (size_t)(k0 + rrB + br8) * 2304, Bs + rrB * 64);
    }
    __syncthreads();
#pragma unroll
    for (int half = 0; half < 2; half++) {
      float chunk[4][4] = {};
#pragma unroll
      for (int kg = 0; kg < 4; kg++) {
        int kc = half * 4 + kg;
        float4 a4[4];
#pragma unroll
        for (int i = 0; i < 4; i++) {
          int row = ty * 4 + i;
          a4[i] = *(const float4*)&As[row * 32 + ((kc ^ (row & 7)) << 2)];
        }
#pragma unroll
        for (int c = 0; c < 4; c++) {
          float4 bb = *(const float4*)&Bs[(kc * 4 + c) * 64 + tx * 4];
          float aa[4];
#pragma unroll
          for (int i = 0; i < 4; i++)
            aa[i] = (c == 0) ? a4[i].x : (c == 1) ? a4[i].y
                  : (c == 2) ? a4[i].z : a4[i].w;
#pragma unroll
          for (int i = 0; i < 4; i++) {
            chunk[i][0] = fmaf(aa[i], bb.x, chunk[i][0]);
            chunk[i][1] = fmaf(aa[i], bb.y, chunk[i][1]);
            chunk[i][2] = fmaf(aa[i], bb.z, chunk[i][2]);
            chunk[i][3] = fmaf(aa[i], bb.w, chunk[i][3]);
          }
        }
      }
#pragma unroll
      for (int i = 0; i < 4; i++)
#pragma unroll
        for (int j = 0; j < 4; j++) master[i][j] += (double)chunk[i][j];
    }
    __syncthreads();
  }
  int n0 = bn0 + tx * 4;
  int h = n0 >> 6, d = n0 & 63;
#pragma unroll
  for (int i = 0; i < 4; i++) {
    int m = bm0 + ty * 4 + i;
    float4 v;
    v.x = (float)master[i][0] + bias[colOff + n0];
    v.y = (float)master[i][1] + bias[colOff + n0 + 1];
    v.z = (float)master[i][2] + bias[colOff + n0 + 2];
    v.w = (float)master[i][3] + bias[colOff + n0 + 3];
    if (ROWMAP) {
      int b = m >> 6, nr = m & 63;
      *(float4*)(Dst + (((size_t)(b * 12 + h) * 64 + nr) << 6) + d) = v;
    } else {
      int b = m / 320, nr = m - b * 320;
      *(float4*)(Dst + (((size_t)(b * 12 + h) * 320 + nr) << 6) + d) = v;
    }
  }
}

// ---------------------------------------------------------------------------
// attn_t: PRECISE t-row attention (standalone, round-12 proven). Grid 384.
// ---------------------------------------------------------------------------
__global__ __launch_bounds__(256)
void attn_t_kernel(const float* __restrict__ Qt, const float* __restrict__ Kb,
                   const float* __restrict__ Vb, float* __restrict__ attn,
                   unsigned short* __restrict__ xa) {
  __shared__ float Qs[64][68];
  __shared__ float Ks[64][68];
  float (*Ps)[68] = Qs;
  int bh = blockIdx.x;
  int h = bh % 12, b = bh / 12;
  int t = threadIdx.x;
  int tx = t & 15, ty = t >> 4;
  const float* Qg = Qt + (size_t)bh * 4096;
  const float* Kg = Kb + (((size_t)bh * 320) << 6);
  const float* Vg = Vb + (((size_t)bh * 320) << 6);
  float* attn_bh = attn + ((size_t)bh * 320) * 320;

  {
    int r = t >> 2, c = (t & 3) * 16;
    const float* src = Qg + (r << 6) + c;
#pragma unroll
    for (int i = 0; i < 4; i++)
      *(float4*)&Qs[r][c + i * 4] = *(const float4*)(src + i * 4);
  }

  float s[4][20];
  float mrow[4] = {-1e30f, -1e30f, -1e30f, -1e30f};

#pragma unroll
  for (int kc = 0; kc < 5; ++kc) {
    __syncthreads();
    {
      int r = t >> 2, c = (t & 3) * 16;
      const float* src = Kg + ((size_t)(kc * 64 + r) << 6) + c;
#pragma unroll
      for (int i = 0; i < 4; i++)
        *(float4*)&Ks[r][c + i * 4] = *(const float4*)(src + i * 4);
    }
    __syncthreads();
    float acc[4][4] = {};
#pragma unroll 4
    for (int d0 = 0; d0 < 64; d0 += 4) {
      float4 qv[4], kv[4];
#pragma unroll
      for (int i = 0; i < 4; i++) qv[i] = *(const float4*)&Qs[ty * 4 + i][d0];
#pragma unroll
      for (int j = 0; j < 4; j++) kv[j] = *(const float4*)&Ks[j * 16 + tx][d0];
#pragma unroll
      for (int i = 0; i < 4; i++)
#pragma unroll
        for (int j = 0; j < 4; j++) {
          acc[i][j] = fmaf(qv[i].x, kv[j].x, acc[i][j]);
          acc[i][j] = fmaf(qv[i].y, kv[j].y, acc[i][j]);
          acc[i][j] = fmaf(qv[i].z, kv[j].z, acc[i][j]);
          acc[i][j] = fmaf(qv[i].w, kv[j].w, acc[i][j]);
        }
    }
#pragma unroll
    for (int i = 0; i < 4; i++) {
      float sx = acc[i][0] * 0.125f, sy = acc[i][1] * 0.125f;
      float sz = acc[i][2] * 0.125f, sw = acc[i][3] * 0.125f;
      mrow[i] = fmaxf(mrow[i], fmaxf(fmaxf(sx, sy), fmaxf(sz, sw)));
      s[i][kc * 4 + 0] = sx; s[i][kc * 4 + 1] = sy;
      s[i][kc * 4 + 2] = sz; s[i][kc * 4 + 3] = sw;
    }
  }
#pragma unroll
  for (int i = 0; i < 4; i++) {
    mrow[i] = fmaxf(mrow[i], __shfl_xor(mrow[i], 1, 16));
    mrow[i] = fmaxf(mrow[i], __shfl_xor(mrow[i], 2, 16));
    mrow[i] = fmaxf(mrow[i], __shfl_xor(mrow[i], 4, 16));
    mrow[i] = fmaxf(mrow[i], __shfl_xor(mrow[i], 8, 16));
  }

  double lsum[4] = {0.0, 0.0, 0.0, 0.0};
#pragma unroll
  for (int i = 0; i < 4; i++)
#pragma unroll
    for (int c = 0; c < 20; c++) {
      float e = expf(s[i][c] - mrow[i]);
      s[i][c] = e;
      lsum[i] += (double)e;
    }
#pragma unroll
  for (int i = 0; i < 4; i++) {
    lsum[i] += __shfl_xor(lsum[i], 1, 16);
    lsum[i] += __shfl_xor(lsum[i], 2, 16);
    lsum[i] += __shfl_xor(lsum[i], 4, 16);
    lsum[i] += __shfl_xor(lsum[i], 8, 16);
  }
  float inv[4];
#pragma unroll
  for (int i = 0; i < 4; i++) inv[i] = (float)(1.0 / lsum[i]);

#pragma unroll
  for (int i = 0; i < 4; i++) {
    float* rp = attn_bh + (size_t)(ty * 4 + i) * 320;
#pragma unroll
    for (int kc = 0; kc < 5; kc++)
#pragma unroll
      for (int j = 0; j < 4; j++)
        rp[kc * 64 + j * 16 + tx] = s[i][kc * 4 + j] * inv[i];
  }

  float acc2[4][4] = {};
  for (int kc = 0; kc < 5; ++kc) {
    __syncthreads();
    {
      int r = t >> 2, c = (t & 3) * 16;
      const float* src = Vg + ((size_t)(kc * 64 + r) << 6) + c;
#pragma unroll
      for (int i = 0; i < 4; i++)
        *(float4*)&Ks[r][c + i * 4] = *(const float4*)(src + i * 4);
    }
#pragma unroll
    for (int i = 0; i < 4; i++)
#pragma unroll
      for (int j = 0; j < 4; j++)
        Ps[ty * 4 + i][j * 16 + tx] = s[i][kc * 4 + j] * inv[i];
    __syncthreads();
#pragma unroll 4
    for (int kk4 = 0; kk4 < 16; ++kk4) {
      float4 pv[4], vv[4];
#pragma unroll
      for (int i = 0; i < 4; i++)
        pv[i] = *(const float4*)&Ps[ty * 4 + i][kk4 * 4];
#pragma unroll
      for (int l = 0; l < 4; l++) vv[l] = *(const float4*)&Ks[kk4 * 4 + l][tx * 4];
#pragma unroll
      for (int i = 0; i < 4; i++) {
        acc2[i][0] = fmaf(pv[i].x, vv[0].x, acc2[i][0]);
        acc2[i][1] = fmaf(pv[i].x, vv[0].y, acc2[i][1]);
        acc2[i][2] = fmaf(pv[i].x, vv[0].z, acc2[i][2]);
        acc2[i][3] = fmaf(pv[i].x, vv[0].w, acc2[i][3]);
        acc2[i][0] = fmaf(pv[i].y, vv[1].x, acc2[i][0]);
        acc2[i][1] = fmaf(pv[i].y, vv[1].y, acc2[i][1]);
        acc2[i][2] = fmaf(pv[i].y, vv[1].z, acc2[i][2]);
        acc2[i][3] = fmaf(pv[i].y, vv[1].w, acc2[i][3]);
        acc2[i][0] = fmaf(pv[i].z, vv[2].x, acc2[i][0]);
        acc2[i][1] = fmaf(pv[i].z, vv[2].y, acc2[i][1]);
        acc2[i][2] = fmaf(pv[i].z, vv[2].z, acc2[i][2]);
        acc2[i][3] = fmaf(pv[i].z, vv[2].w, acc2[i][3]);
        acc2[i][0] = fmaf(pv[i].w, vv[3].x, acc2[i][0]);
        acc2[i][1] = fmaf(pv[i].w, vv[3].y, acc2[i][1]);
        acc2[i][2] = fmaf(pv[i].w, vv[3].z, acc2[i][2]);
        acc2[i][3] = fmaf(pv[i].w, vv[3].w, acc2[i][3]);
      }
    }
  }
#pragma unroll
  for (int i = 0; i < 4; i++) {
    unsigned short* dst = xa + (size_t)(b * 320 + ty * 4 + i) * 768 + h * 64 + tx * 4;
    uint2 pk;
    pk.x = (unsigned)f2bf(acc2[i][0]) | ((unsigned)f2bf(acc2[i][1]) << 16);
    pk.y = (unsigned)f2bf(acc2[i][2]) | ((unsigned)f2bf(acc2[i][3]) << 16);
    *(uint2*)dst = pk;
  }
}

// ---------------------------------------------------------------------------
// attn_s: bf16 MFMA s-row attention (standalone, round-12 proven). Grid 1536.
// ---------------------------------------------------------------------------
__global__ __launch_bounds__(256)
void attn_s_kernel(const unsigned short* __restrict__ Qbf,
                   const unsigned short* __restrict__ Kbf,
                   const unsigned short* __restrict__ Vtbf,
                   float* __restrict__ attn, unsigned short* __restrict__ xa) {
  __shared__ unsigned short lds_[24576];   // 48 KB
  unsigned short* Ql  = lds_;
  unsigned short* Kl  = lds_ + 4096;
  unsigned short* Pl  = lds_;
  unsigned short* Vtl = lds_ + 20480;

  int bid = blockIdx.x;
  int sqt = bid / 384, bh = bid % 384;
  int h = bh % 12, b = bh / 12;
  int q0 = 64 + sqt * 64;
  int tid = threadIdx.x;
  int lane = tid & 63, wid = tid >> 6;
  int r8 = lane >> 3, csw = lane & 7, csrc = csw ^ r8;
  int mrow = lane & 15, kch = lane >> 4, key = mrow & 7;

  const unsigned short* Qg = Qbf + ((size_t)bh * 320 + q0) * 64 + csrc * 8;
  const unsigned short* Kg = Kbf + (size_t)bh * 320 * 64 + csrc * 8;
#pragma unroll
  for (int i = 0; i < 2; i++) {
    int rr = wid * 16 + i * 8;
    gload_lds16(Qg + (size_t)(rr + r8) * 64, Ql + rr * 64);
  }
#pragma unroll
  for (int i = 0; i < 10; i++) {
    int rr = wid * 80 + i * 8;
    gload_lds16(Kg + (size_t)(rr + r8) * 64, Kl + rr * 64);
  }
  __syncthreads();

  bf16x8 af[2];
#pragma unroll
  for (int ks = 0; ks < 2; ks++)
    af[ks] = *reinterpret_cast<const bf16x8*>(
        &Ql[(wid * 16 + mrow) * 64 + (((ks * 4 + kch) ^ key) << 3)]);
  f32x4 acc[20] = {};
#pragma unroll
  for (int nt = 0; nt < 20; nt++) {
#pragma unroll
    for (int ks = 0; ks < 2; ks++) {
      bf16x8 bk = *reinterpret_cast<const bf16x8*>(
          &Kl[(nt * 16 + mrow) * 64 + (((ks * 4 + kch) ^ key) << 3)]);
      acc[nt] = __builtin_amdgcn_mfma_f32_16x16x32_bf16(af[ks], bk, acc[nt], 0, 0, 0);
    }
  }

  float m4[4] = {-1e30f, -1e30f, -1e30f, -1e30f};
#pragma unroll
  for (int nt = 0; nt < 20; nt++)
#pragma unroll
    for (int j = 0; j < 4; j++) {
      acc[nt][j] *= 0.125f;
      m4[j] = fmaxf(m4[j], acc[nt][j]);
    }
#pragma unroll
  for (int j = 0; j < 4; j++) {
    m4[j] = fmaxf(m4[j], __shfl_xor(m4[j], 1, 16));
    m4[j] = fmaxf(m4[j], __shfl_xor(m4[j], 2, 16));
    m4[j] = fmaxf(m4[j], __shfl_xor(m4[j], 4, 16));
    m4[j] = fmaxf(m4[j], __shfl_xor(m4[j], 8, 16));
  }
  float s4[4] = {0.0f, 0.0f, 0.0f, 0.0f};
#pragma unroll
  for (int nt = 0; nt < 20; nt++)
#pragma unroll
    for (int j = 0; j < 4; j++) {
      float e = expf(acc[nt][j] - m4[j]);
      acc[nt][j] = e;
      s4[j] += e;
    }
#pragma unroll
  for (int j = 0; j < 4; j++) {
    s4[j] += __shfl_xor(s4[j], 1, 16);
    s4[j] += __shfl_xor(s4[j], 2, 16);
    s4[j] += __shfl_xor(s4[j], 4, 16);
    s4[j] += __shfl_xor(s4[j], 8, 16);
  }
  float inv4[4];
#pragma unroll
  for (int j = 0; j < 4; j++) inv4[j] = 1.0f / s4[j];

  __syncthreads();

  float* attn_q = attn + ((size_t)bh * 320 + q0) * 320;
#pragma unroll
  for (int j = 0; j < 4; j++) {
    int r = wid * 16 + (lane >> 4) * 4 + j;
    float* rp = attn_q + (size_t)r * 320;
    int rkey = r & 7;
#pragma unroll
    for (int nt = 0; nt < 20; nt++) {
      float p = acc[nt][j] * inv4[j];
      int k = nt * 16 + mrow;
      rp[k] = p;
      int c = k >> 3;
      int cs = (c & 0x38) | ((c ^ rkey) & 7);
      Pl[r * 320 + cs * 8 + (k & 7)] = f2bf(p);
    }
  }

  f32x4 acc2[4] = {};
  const unsigned short* Vg = Vtbf + (size_t)bh * 64 * 320 + csrc * 8;
  for (int kc = 0; kc < 5; kc++) {
    __syncthreads();
#pragma unroll
    for (int i = 0; i < 2; i++) {
      int rr = wid * 16 + i * 8;
      gload_lds16(Vg + (size_t)(rr + r8) * 320 + kc * 64, Vtl + rr * 64);
    }
    __syncthreads();
#pragma unroll
    for (int ks = 0; ks < 2; ks++) {
      int cc = (ks * 4 + kch) ^ key;
      bf16x8 ap = *reinterpret_cast<const bf16x8*>(
          &Pl[(wid * 16 + mrow) * 320 + ((kc * 8 + cc) << 3)]);
#pragma unroll
      for (int nd = 0; nd < 4; nd++) {
        bf16x8 bv = *reinterpret_cast<const bf16x8*>(
            &Vtl[(nd * 16 + mrow) * 64 + (cc << 3)]);
        acc2[nd] = __builtin_amdgcn_mfma_f32_16x16x32_bf16(ap, bv, acc2[nd], 0, 0, 0);
      }
    }
  }
#pragma unroll
  for (int nd = 0; nd < 4; nd++)
#pragma unroll
    for (int j = 0; j < 4; j++) {
      int r = wid * 16 + (lane >> 4) * 4 + j;
      int d = nd * 16 + mrow;
      xa[((size_t)(b * 320) + q0 + r) * 768 + h * 64 + d] = f2bf(acc2[nd][j]);
    }
}

// ---------------------------------------------------------------------------
// w_ts (standalone)
// ---------------------------------------------------------------------------
__global__ __launch_bounds__(256)
void wts_kernel(const float* __restrict__ attn, float* __restrict__ wts) {
  int bid = blockIdx.x;
  int tt = bid & 63, b = bid >> 6;
  int s = threadIdx.x;
  float acc = 0.0f;
  const float* base = attn + (((size_t)(b * 12)) * 320 + tt) * 320 + 64 + s;
#pragma unroll
  for (int h = 0; h < 12; h++) acc += base[(size_t)h * 320 * 320];
  acc *= (1.0f / 12.0f);
  __shared__ float red[256];
  red[s] = acc; __syncthreads();
  for (int st = 128; st > 0; st >>= 1) {
    if (s < st) red[s] = fmaxf(red[s], red[s + st]);
    __syncthreads();
  }
  float m = red[0]; __syncthreads();
  float e = expf(acc - m);
  red[s] = e; __syncthreads();
  for (int st = 128; st > 0; st >>= 1) {
    if (s < st) red[s] += red[s + st];
    __syncthreads();
  }
  wts[(size_t)bid * 256 + s] = e / red[0];
}

// out_t[b,t,c] = sum_s wts[b,t,s] * sup[b,64+s,c]
__global__ __launch_bounds__(256)
void out_t_kernel(const float* __restrict__ wts, const float* __restrict__ sup,
                  float* __restrict__ x3) {
  int idx = blockIdx.x * 256 + threadIdx.x;
  int c = idx % 768;
  int tt = (idx / 768) % 64;
  int b = idx / (768 * 64);
  const float* wrow = wts + (size_t)(b * 64 + tt) * 256;
  const float* sp = sup + ((size_t)(b * 320 + 64)) * 768 + c;
  float acc = 0.0f;
  for (int s = 0; s < 256; s++) acc = fmaf(wrow[s], sp[(size_t)s * 768], acc);
  x3[((size_t)(b * 320 + tt)) * 768 + c] = acc;
}

// out_s[b,s,c] = sum_t wts[b,t,s] * sup[b,t,c]
__global__ __launch_bounds__(256)
void out_s_kernel(const float* __restrict__ wts, const float* __restrict__ sup,
                  float* __restrict__ x3) {
  int idx = blockIdx.x * 256 + threadIdx.x;
  int c = idx % 768;
  int s = (idx / 768) % 256;
  int b = idx / (768 * 256);
  const float* wp = wts + (size_t)(b * 64) * 256 + s;
  const float* sp = sup + ((size_t)(b * 320)) * 768 + c;
  float acc = 0.0f;
#pragma unroll 4
  for (int tt = 0; tt < 64; tt++) acc = fmaf(wp[(size_t)tt * 256], sp[(size_t)tt * 768], acc);
  x3[((size_t)(b * 320 + 64 + s)) * 768 + c] = acc;
}

// ---------------------------------------------------------------------------
// score partials (double) + final stable descending rank-sort + index outs.
// ---------------------------------------------------------------------------
__global__ __launch_bounds__(256)
void score_part_kernel(const float* __restrict__ attn, double* __restrict__ part) {
  int h = blockIdx.x, b = blockIdx.y;
  int s = threadIdx.x;
  const float* base = attn + (((size_t)(b * 12 + h)) * 320) * 320 + 64 + s;
  double acc = 0.0;
  for (int tt = 0; tt < 64; tt++) acc += (double)base[(size_t)tt * 320];
  part[((size_t)(b * 12 + h)) * 256 + s] = acc;
}

__global__ __launch_bounds__(256)
void score_final_kernel(const double* __restrict__ part, const int* __restrict__ git,
                        const int* __restrict__ gis, int* __restrict__ order_ws,
                        float* __restrict__ out_git, float* __restrict__ out_gs,
                        float* __restrict__ out_rm) {
  int b = blockIdx.x, s = threadIdx.x;
  double acc = 0.0;
#pragma unroll
  for (int h = 0; h < 12; h++) acc += part[((size_t)(b * 12 + h)) * 256 + s];
  __shared__ double sc[256];
  __shared__ int ord[256];
  sc[s] = acc;
  __syncthreads();
  double my = sc[s];
  int r = 0;
  for (int i = 0; i < 256; i++) {
    double si = sc[i];
    r += (si > my) || (si == my && i < s);
  }
  ord[r] = s;
  __syncthreads();
  int o = ord[s];
  order_ws[b * 256 + s] = o;
  if (s < NKEEP) out_gs[b * NKEEP + s] = (float)gis[b * 256 + o];
  else           out_rm[b * NREM + (s - NKEEP)] = (float)o;
  if (s < 64)    out_git[b * 64 + s] = (float)git[b * 64 + s];
}

// Final row gather
__global__ __launch_bounds__(256)
void gather_kernel(const float* __restrict__ x3, const int* __restrict__ git,
                   const int* __restrict__ order_ws, float* __restrict__ out) {
  int bid = blockIdx.x;
  int j = bid % NOUT_ROWS, b = bid / NOUT_ROWS;
  int src = (j < 64) ? git[b * 64 + j] : (order_ws[b * 256 + (j - 64)] + 64);
  const float* p = x3 + ((size_t)(b * 320 + src)) * 768;
  float* o = out + ((size_t)(b * NOUT_ROWS + j)) * 768;
  int tid = threadIdx.x;
  o[tid] = p[tid]; o[tid + 256] = p[tid + 256]; o[tid + 512] = p[tid + 512];
}

// ---------------------------------------------------------------------------
extern "C" void kernel_launch(void* const* d_in, const int* in_sizes, int n_in,
                              void* d_out, int out_size, void* d_ws, size_t ws_size,
                              hipStream_t stream) {
  (void)in_sizes; (void)n_in; (void)out_size; (void)ws_size;
  const float* x      = (const float*)d_in[0];
  const int*   git    = (const int*)d_in[1];
  const int*   gis    = (const int*)d_in[2];
  const float* n1s    = (const float*)d_in[3];
  const float* n1b    = (const float*)d_in[4];
  const float* qkv_w  = (const float*)d_in[5];
  const float* qkv_b  = (const float*)d_in[6];
  const float* proj_w = (const float*)d_in[7];
  const float* proj_b = (const float*)d_in[8];
  const float* n2s    = (const float*)d_in[9];
  const float* n2b    = (const float*)d_in[10];
  const float* fc1_w  = (const float*)d_in[11];
  const float* fc1_b  = (const float*)d_in[12];
  const float* fc2_w  = (const float*)d_in[13];
  const float* fc2_b  = (const float*)d_in[14];
  const float* gcn_w  = (const float*)d_in[15];
  const float* gcn_b  = (const float*)d_in[16];
  const float* n3s    = (const float*)d_in[17];
  const float* n3b    = (const float*)d_in[18];

  float* out     = (float*)d_out;
  float* out_x   = out;                 // 32*243*768
  float* out_git = out + 5971968;       // 2048
  float* out_gs  = out + 5974016;       // 5728
  float* out_rm  = out + 5979744;       // 2464
  float* attn    = out + 5982208;       // 32*12*320*320

  float* w      = (float*)d_ws;
  float* bufA   = w;                        // 7,864,320 floats
  float* bufB   = w + 7864320;              // 7,864,320 floats
  float* bufBIG = w + 15728640;             // 31,457,280 floats
  // phase 1 overlay of bufBIG
  float* Qt   = bufBIG;                                         // compact t-row Q
  unsigned short* Vtbf = (unsigned short*)(bufBIG + 1572864);
  float* Kbuf = bufBIG + 7864320;
  float* Vbuf = bufBIG + 15728640;
  unsigned short* ln1_bf = (unsigned short*)(bufBIG + 23592960);
  unsigned short* Qbf = (unsigned short*)bufB;
  unsigned short* Kbf = (unsigned short*)(bufB + 3932160);
  // phase 2 overlay of bufBIG
  unsigned short* f1_bf = (unsigned short*)bufBIG;
  unsigned short* x2_bf = (unsigned short*)(bufBIG + 15728640);
  float* x3 = bufBIG + 19660800;
  // persistent bf16 weights
  unsigned short* wbf = (unsigned short*)(bufBIG + 27525120);
  unsigned short* proj_wt = wbf;
  unsigned short* fc1_wt  = wbf + 589824;
  unsigned short* fc2_wt  = fc1_wt + 2359296;
  unsigned short* gcn_wt  = fc2_wt + 2359296;
  unsigned short* qkv_wt  = gcn_wt + 589824;
  unsigned short* xa_bf = (unsigned short*)bufA;
  unsigned short* h2_bf = (unsigned short*)bufA;
  float* wts    = bufBIG + 31457280;
  int*   order_ws = (int*)(wts + 524288);
  double* partd  = (double*)(wts + 524288 + 8192);

  const int M = 10240;  // 32*320

  // 0. MERGED bf16 weight transposes (one dispatch, 7488 blocks)
  wtrans_all_kernel<<<dim3(7488), dim3(256), 0, stream>>>(
      proj_w, proj_wt, fc1_w, fc1_wt, fc2_w, fc2_wt, gcn_w, gcn_wt, qkv_w, qkv_wt);

  // 1. h = LN1(x): fp32 + bf16
  ln_kernel<0, 2><<<dim3(M), dim3(256), 0, stream>>>(x, n1s, n1b, bufA, ln1_bf);
  // 2a. full qkv in bf16 MFMA
  gemm_qkv_bf16_kernel<<<dim3(80, 18), dim3(256), 0, stream>>>(
      ln1_bf, qkv_wt, qkv_b, Qbf, Kbf, Vbuf, Vtbf);
  // 2b. precise K (templated standalone — 72 VGPR)
  gemm_prec_kernel<0><<<dim3(160, 12), dim3(256), 0, stream>>>(
      bufA, qkv_w, qkv_b, 768, Kbuf);
  // 2c. precise Qt
  gemm_prec_kernel<1><<<dim3(32, 12), dim3(256), 0, stream>>>(
      bufA, qkv_w, qkv_b, 0, Qt);
  // 3a. precise t-row attention
  attn_t_kernel<<<dim3(384), dim3(256), 0, stream>>>(
      Qt, Kbuf, Vbuf, attn, xa_bf);
  // 3b. bf16 MFMA s-row attention
  attn_s_kernel<<<dim3(1536), dim3(256), 0, stream>>>(
      Qbf, Kbf, Vtbf, attn, xa_bf);
  // 4. x1 = x + xa @ proj_w + proj_b (fp32 -> bufB; Qbf/Kbf now dead)
  gemm_bf16_kernel<0, 1, 0, 64><<<dim3(M / 128, 768 / 64), dim3(256), 0, stream>>>(
      xa_bf, proj_wt, proj_b, x, bufB, M, 768, 768);
  // 5. h2 = LN2(x1) -> bf16
  ln_kernel<0, 1><<<dim3(M), dim3(256), 0, stream>>>(bufB, n2s, n2b, h2_bf, nullptr);
  // 6. f1 = gelu(h2 @ fc1_w + fc1_b) -> bf16
  gemm_bf16_kernel<1, 0, 1, 128><<<dim3(M / 128, 3072 / 128), dim3(256), 0, stream>>>(
      h2_bf, fc1_wt, fc1_b, nullptr, f1_bf, M, 768, 3072);
  // 7. x2 = x1 + f1 @ fc2_w + fc2_b -> bf16
  gemm_bf16_kernel<0, 1, 1, 64><<<dim3(M / 128, 768 / 64), dim3(256), 0, stream>>>(
      f1_bf, fc2_wt, fc2_b, bufB, x2_bf, M, 3072, 768);
  // 8. w_ts
  wts_kernel<<<dim3(32 * 64), dim3(256), 0, stream>>>(attn, wts);
  // 9. support = x2 @ gcn_w + gcn_b (fp32 -> bufA)
  gemm_bf16_kernel<0, 0, 0, 64><<<dim3(M / 128, 768 / 64), dim3(256), 0, stream>>>(
      x2_bf, gcn_wt, gcn_b, nullptr, bufA, M, 768, 768);
  // 10/11. x3 = concat(out_t, out_s)
  out_t_kernel<<<dim3(32 * 64 * 768 / 256), dim3(256), 0, stream>>>(wts, bufA, x3);
  out_s_kernel<<<dim3(32 * 256 * 768 / 256), dim3(256), 0, stream>>>(wts, bufA, x3);
  // 12. x3 = x3 + LN3(x3)
  ln_kernel<1, 0><<<dim3(M), dim3(256), 0, stream>>>(x3, n3s, n3b, x3, nullptr);
  // 13. score partials (double) + final sort
  score_part_kernel<<<dim3(12, 32), dim3(256), 0, stream>>>(attn, partd);
  score_final_kernel<<<dim3(32), dim3(256), 0, stream>>>(partd, git, gis, order_ws,
                                                         out_git, out_gs, out_rm);
  // 14. gather kept rows
  gather_kernel<<<dim3(32 * NOUT_ROWS), dim3(256), 0, stream>>>(x3, git,
                                                                order_ws, out_x);
}